// Round 1
// baseline (193.363 us; speedup 1.0000x reference)
//
#include <hip/hip_runtime.h>

// R8: (1) attn: 512-thread 8-wave blocks (4 q-quarters x 2 key-halves) ->
// 16 waves/CU (4/SIMD, was 2) to hide LDS/EXP latency; key mask folded into
// the QK MFMA accumulator init (kmask buffer now stores 0/-1e30 bias; kills
// the post-exp multiply); softmax denominator l computed by one extra MFMA
// against a ones B-operand (kills scalar add chains + epilogue shuffles).
// (2) proj: A staged as [128][32] f32 with XOR-swizzled source (old
// [2][128][16] layout put the f32x4 fragment reads on 4 bank-groups ->
// 16-way conflicts; now 8 groups / 8-way like the proven K layout).

typedef __attribute__((ext_vector_type(8))) __bf16 bf16x8;
typedef __attribute__((ext_vector_type(4))) float f32x4;

#if __has_builtin(__builtin_amdgcn_exp2f)
#define EXP2F __builtin_amdgcn_exp2f
#else
#define EXP2F exp2f
#endif

#define QSCALE (0.125f * 1.4426950408889634f)  // fold /sqrt(64) and ln->log2

__device__ __forceinline__ unsigned short f2bf(float f) {
  return __builtin_bit_cast(unsigned short, (__bf16)f);
}
__device__ __forceinline__ unsigned pk2(float a, float b) {
  return (unsigned)f2bf(a) | ((unsigned)f2bf(b) << 16);
}
__device__ __forceinline__ f32x4 mfma16(bf16x8 a, bf16x8 b, f32x4 c) {
  return __builtin_amdgcn_mfma_f32_16x16x32_bf16(a, b, c, 0, 0, 0);
}
__device__ __forceinline__ bf16x8 ld_bf8(const unsigned short* p) {
  return *(const bf16x8*)p;
}
// async global->LDS, 16 B per lane; LDS dst is wave-uniform base + lane*16
__device__ __forceinline__ void g2l16(const void* g, void* l) {
  __builtin_amdgcn_global_load_lds(
      (const __attribute__((address_space(1))) void*)g,
      (__attribute__((address_space(3))) void*)l, 16, 0, 0);
}

// ---------------------------------------------------------------------------
// Kernel 1: transpose + convert the three 512x512 weight matrices to bf16,
// layout Wt[z][n][k] (n-major) so MFMA B-fragments read contiguous k.
// ---------------------------------------------------------------------------
__global__ __launch_bounds__(256) void wt_kernel(const float* __restrict__ Wq,
                                                 const float* __restrict__ Wk,
                                                 const float* __restrict__ Wv,
                                                 unsigned short* __restrict__ Wt) {
  int idx = blockIdx.x * 256 + threadIdx.x;
  int o = idx * 8;
  int z = o >> 18;
  int rem = o & 262143;
  int n = rem >> 9;
  int k0 = rem & 511;
  const float* W = (z == 0) ? Wq : ((z == 1) ? Wk : Wv);
  unsigned int w[4];
#pragma unroll
  for (int i = 0; i < 4; ++i) {
    unsigned short lo = f2bf(W[(k0 + 2 * i) * 512 + n]);
    unsigned short hi = f2bf(W[(k0 + 2 * i + 1) * 512 + n]);
    w[i] = (unsigned)lo | ((unsigned)hi << 16);
  }
  *(uint4*)(Wt + o) = make_uint4(w[0], w[1], w[2], w[3]);
}

// ---------------------------------------------------------------------------
// Kernel 2: QKV projection as m97-style GEMM + fused padding-mask compute.
// Grid (192 m-blocks, 4 n-blocks); z = m-block/64. Tile 128x128, BK=32.
// A staged as Asm[128][32] f32 with source-side XOR swizzle
// (slot = chunk ^ (row&7), 16B chunks) so the per-mt f32x4 fragment reads
// spread over all 8 bank-groups. Blocks with n0==0 && z<2 also accumulate
// raw-X row sums from the staged fp32 A-tiles (wn==0 waves) and write
// qmask (0/1, multiplicative) and kbias (0/-1e30, folded into QK acc init).
// V stored transposed with the permuted intra-32-key order
// (pos = quad*8 + sub*4 + r), matching attn's P register-repack k-order.
// ---------------------------------------------------------------------------
__global__ __launch_bounds__(256, 3) void proj_kernel(
    const float* __restrict__ Xq, const float* __restrict__ Xk,
    const float* __restrict__ Xv, const float* __restrict__ bq,
    const float* __restrict__ bk, const float* __restrict__ bv,
    const unsigned short* __restrict__ Wt, unsigned short* __restrict__ Qb,
    unsigned short* __restrict__ Kb, unsigned short* __restrict__ Vt,
    float* __restrict__ qmask, float* __restrict__ kbias) {
  __shared__ float Asm[128][32];
  __shared__ unsigned short Bsm[128][32];

  int tid = threadIdx.x;
  int m0g = blockIdx.x * 128;
  int z = m0g >> 13;
  int m0 = m0g & 8191;
  int n0 = blockIdx.y * 128;
  const float* X = (z == 0) ? Xq : ((z == 1) ? Xk : Xv);
  const float* bias = (z == 0) ? bq : ((z == 1) ? bk : bv);
  const unsigned short* Wz = Wt + z * 262144;

  int w = tid >> 6, lane = tid & 63;
  int wm = w >> 1, wn = w & 1;
  int mrow = lane & 15, quad = lane >> 4;
  int m7 = mrow & 7;

  // A staging: thread -> (row = tid>>3 in 0..31, slot = tid&7); source k-chunk
  // is XOR-swizzled so LDS stays linear (g2l16 constraint) and reads unswizzle.
  int arow = tid >> 3, aslot = tid & 7;
  const float* gA = X + (m0 + arow) * 512 + ((aslot ^ (arow & 7)) * 4);
  char* lA = (char*)&Asm[0][0] + tid * 16;

  int srow = tid >> 2, schk = tid & 3;
  const unsigned short* gB = Wz + (n0 + srow) * 512 + schk * 8;
  char* lB = (char*)&Bsm[0][0] + tid * 16;

  const unsigned short* rB = &Bsm[0][quad * 8];

  f32x4 zero = {0.f, 0.f, 0.f, 0.f};
  f32x4 acc[4][4];
#pragma unroll
  for (int i = 0; i < 4; ++i)
#pragma unroll
    for (int j = 0; j < 4; ++j) acc[i][j] = zero;

  bool domask = (z < 2) && (n0 == 0) && (wn == 0);
  float rsum[4] = {0.f, 0.f, 0.f, 0.f};

  for (int kc = 0; kc < 16; ++kc) {
    int ko = kc * 32;
#pragma unroll
    for (int j = 0; j < 4; ++j) g2l16(gA + ko + j * 32 * 512, lA + j * 4096);
    g2l16(gB + ko, lB);
    g2l16(gB + ko + 64 * 512, lB + 4096);
    __syncthreads();

    bf16x8 af[4], bfr[4];
#pragma unroll
    for (int mt = 0; mt < 4; ++mt) {
      const float* pa = &Asm[wm * 64 + mt * 16 + mrow][0];
      f32x4 lo = *(const f32x4*)(pa + ((2 * quad) ^ m7) * 4);
      f32x4 hi = *(const f32x4*)(pa + ((2 * quad + 1) ^ m7) * 4);
      if (domask)
        rsum[mt] += lo[0] + lo[1] + lo[2] + lo[3] + hi[0] + hi[1] + hi[2] + hi[3];
      bf16x8 t;
      t[0] = (__bf16)lo[0]; t[1] = (__bf16)lo[1];
      t[2] = (__bf16)lo[2]; t[3] = (__bf16)lo[3];
      t[4] = (__bf16)hi[0]; t[5] = (__bf16)hi[1];
      t[6] = (__bf16)hi[2]; t[7] = (__bf16)hi[3];
      af[mt] = t;
    }
#pragma unroll
    for (int nt = 0; nt < 4; ++nt)
      bfr[nt] = ld_bf8(rB + (wn * 64 + nt * 16 + mrow) * 32);
#pragma unroll
    for (int mt = 0; mt < 4; ++mt)
#pragma unroll
      for (int nt = 0; nt < 4; ++nt)
        acc[mt][nt] = mfma16(af[mt], bfr[nt], acc[mt][nt]);
    __syncthreads();
  }

  if (domask) {
    float* msk = (z == 0) ? qmask : kbias;
#pragma unroll
    for (int mt = 0; mt < 4; ++mt) {
      float s = rsum[mt];
      s += __shfl_xor(s, 16);
      s += __shfl_xor(s, 32);
      if (quad == 0) {
        float v;
        if (z == 0)
          v = (s == 0.f) ? 0.f : 1.f;          // qmask: multiplicative
        else
          v = (s == 0.f) ? -1.0e30f : 0.f;     // kbias: added pre-exp
        msk[m0 + wm * 64 + mt * 16 + mrow] = v;
      }
    }
  }

  if (z < 2) {
    unsigned short* dst = (z == 0) ? Qb : Kb;
    float sc = (z == 0) ? QSCALE : 1.0f;
#pragma unroll
    for (int nt = 0; nt < 4; ++nt) {
      int n = n0 + wn * 64 + nt * 16 + mrow;
      float bv_ = bias[n];
#pragma unroll
      for (int mt = 0; mt < 4; ++mt) {
        int m = m0 + wm * 64 + mt * 16 + quad * 4;
#pragma unroll
        for (int r = 0; r < 4; ++r) {
          float v = fmaxf(acc[mt][nt][r] + bv_, 0.f) * sc;
          dst[(m + r) * 512 + n] = f2bf(v);
        }
      }
    }
  } else {
    // V: permuted-transposed store (pos = quad*8 + (mt&1)*4 + r in 32-t group)
#pragma unroll
    for (int nt = 0; nt < 4; ++nt) {
      int n = n0 + wn * 64 + nt * 16 + mrow;
      int hh = n >> 6, jj = n & 63;
      float bv_ = bias[n];
#pragma unroll
      for (int mt = 0; mt < 4; ++mt) {
        int grow = m0 + wm * 64 + mt * 16 + quad * 4;
        int bb = grow >> 11, tl = grow & 2047;
        int pos = (tl & ~31) + quad * 8 + (mt & 1) * 4;
        float p0 = fmaxf(acc[mt][nt][0] + bv_, 0.f);
        float p1 = fmaxf(acc[mt][nt][1] + bv_, 0.f);
        float p2 = fmaxf(acc[mt][nt][2] + bv_, 0.f);
        float p3 = fmaxf(acc[mt][nt][3] + bv_, 0.f);
        *(uint2*)(Vt + ((hh * 4 + bb) * 64 + jj) * 2048 + pos) =
            make_uint2(pk2(p0, p1), pk2(p2, p3));
      }
    }
  }
}

// ---------------------------------------------------------------------------
// Kernel 3: attention. Grid (hb=32, qt=16); block = 128 q, 512 threads,
// 8 waves in 4x2: qh = wave>>1 owns 32 queries, kh2 = wave&1 owns the 64-key
// half of each 128-key chunk. 16 waves/CU (4/SIMD). 16 chunks, ONE barrier
// per chunk, double-buffered K/V LDS (2 x 32 KB) staged via g2l16 with XOR
// swizzle. QK: S^T = K*Q^T seeded with kbias (mask pre-folded). PV:
// O = P*V^T with P as A-operand (register repack, Vt permuted to match);
// l = row-sum of P via MFMA against ones. Epilogue: cross-wave (kh2) O/l
// combine through LDS aliased onto the staging buffers.
// ---------------------------------------------------------------------------
__global__ __launch_bounds__(512, 4) void attn_kernel(
    const unsigned short* __restrict__ Qb, const unsigned short* __restrict__ Kb,
    const unsigned short* __restrict__ Vt, const float* __restrict__ qmask,
    const float* __restrict__ kbias, const float* __restrict__ queries,
    float* __restrict__ out) {
  __shared__ char smem[66560];
  unsigned short* KsmS = (unsigned short*)smem;            // [2][8192] shorts
  unsigned short* VsmS = (unsigned short*)(smem + 32768);  // [2][8192] shorts
  float* Obuf = (float*)smem;                              // [128][65] alias
  float* lbuf = (float*)(smem + 65536);                    // [2][128]

  int hb = blockIdx.x;
  int qt = blockIdx.y;
  int h = hb >> 2, b = hb & 3;
  int q0 = qt * 128;
  int tid = threadIdx.x;
  int w = tid >> 6, lane = tid & 63;
  int qh = w >> 1, kh2 = w & 1;
  int mrow = lane & 15, quad = lane >> 4;

  // staging source pointers (XOR-swizzled slot->chunk); 512 threads:
  // K rows tid>>3 in 0..63 (2 rounds of 64 keys), V dh-rows tid>>4 in 0..31
  // (2 rounds of 32 rows). LDS layouts identical to R7 (read side unchanged).
  const unsigned short* gK =
      Kb + (b * 2048 + (tid >> 3)) * 512 + h * 64 + (((tid & 7) ^ ((tid >> 3) & 7)) * 8);
  const unsigned short* gV =
      Vt + (hb * 64 + (tid >> 4)) * 2048 + (((tid & 15) ^ ((tid >> 4) & 15)) * 8);

  // Q B-frags [n=q qn*16+mrow][k=dh kh*32+quad*8]
  bf16x8 qf[2][2];
  {
    const unsigned short* qp =
        Qb + (b * 2048 + q0 + qh * 32 + mrow) * 512 + h * 64 + quad * 8;
#pragma unroll
    for (int qn = 0; qn < 2; ++qn) {
      qf[qn][0] = ld_bf8(qp + qn * 8192);
      qf[qn][1] = ld_bf8(qp + qn * 8192 + 32);
    }
  }

  bf16x8 onev;
#pragma unroll
  for (int i = 0; i < 8; ++i) onev[i] = (__bf16)1.0f;

  f32x4 zero = {0.f, 0.f, 0.f, 0.f};
  f32x4 oacc[4][2];  // [dt][qn]: col=dh dt*16+mrow, row=q quad*4+r
#pragma unroll
  for (int i = 0; i < 4; ++i)
#pragma unroll
    for (int j = 0; j < 2; ++j) oacc[i][j] = zero;
  f32x4 lacc[2] = {zero, zero};  // row-sums of P, replicated over cols

  const float* kmB = kbias + b * 2048 + kh2 * 64 + quad * 4;
  const int kfrow = kh2 * 64;  // key-row base in Ksm
  const int mlow = mrow & 7;

  // preload chunk 0 into buf 0
#pragma unroll
  for (int j = 0; j < 2; ++j) {
    g2l16(gK + j * 64 * 512, &KsmS[j * 4096 + tid * 8]);
    g2l16(gV + j * 32 * 2048, &VsmS[j * 4096 + tid * 8]);
  }

  for (int it = 0; it < 16; ++it) {
    int bi = it & 1;
    int kb = it * 128;
    __syncthreads();  // drains each wave's own staging DMA; buf bi ready

    if (it < 15) {
      int nkb = kb + 128;
      int nb = 1 - bi;
#pragma unroll
      for (int j = 0; j < 2; ++j) {
        g2l16(gK + (nkb + j * 64) * 512, &KsmS[nb * 8192 + j * 4096 + tid * 8]);
        g2l16(gV + nkb + j * 32 * 2048, &VsmS[nb * 8192 + j * 4096 + tid * 8]);
      }
    }

    // key-bias rows for this wave's lanes (C-init of the QK MFMA)
    f32x4 kmv[4];
#pragma unroll
    for (int mt = 0; mt < 4; ++mt)
      kmv[mt] = *(const f32x4*)(kmB + kb + mt * 16);

#pragma unroll
    for (int kg = 0; kg < 2; ++kg) {
      bf16x8 kfA0 = ld_bf8(&KsmS[bi * 8192 + (kfrow + kg * 32 + mrow) * 64 +
                                 ((quad) ^ mlow) * 8]);
      bf16x8 kfA1 = ld_bf8(&KsmS[bi * 8192 + (kfrow + kg * 32 + mrow) * 64 +
                                 ((4 + quad) ^ mlow) * 8]);
      bf16x8 kfB0 = ld_bf8(&KsmS[bi * 8192 + (kfrow + kg * 32 + 16 + mrow) * 64 +
                                 ((quad) ^ mlow) * 8]);
      bf16x8 kfB1 = ld_bf8(&KsmS[bi * 8192 + (kfrow + kg * 32 + 16 + mrow) * 64 +
                                 ((4 + quad) ^ mlow) * 8]);
      bf16x8 vfg[4];
#pragma unroll
      for (int dt = 0; dt < 4; ++dt)
        vfg[dt] = ld_bf8(&VsmS[bi * 8192 + (dt * 16 + mrow) * 128 +
                               ((kh2 * 8 + kg * 4 + quad) ^ mrow) * 8]);

      f32x4 sA[2], sB[2];
#pragma unroll
      for (int qn = 0; qn < 2; ++qn) {
        f32x4 s0 = mfma16(kfA0, qf[qn][0], kmv[kg * 2]);
        sA[qn] = mfma16(kfA1, qf[qn][1], s0);
        f32x4 s1 = mfma16(kfB0, qf[qn][0], kmv[kg * 2 + 1]);
        sB[qn] = mfma16(kfB1, qf[qn][1], s1);
      }
#pragma unroll
      for (int qn = 0; qn < 2; ++qn) {
        f32x4 p0, p1;
#pragma unroll
        for (int r = 0; r < 4; ++r) {
          p0[r] = EXP2F(sA[qn][r]);
          p1[r] = EXP2F(sB[qn][r]);
        }
        bf16x8 pf = __builtin_bit_cast(
            bf16x8, make_uint4(pk2(p0[0], p0[1]), pk2(p0[2], p0[3]),
                               pk2(p1[0], p1[1]), pk2(p1[2], p1[3])));
        lacc[qn] = mfma16(pf, onev, lacc[qn]);
#pragma unroll
        for (int dt = 0; dt < 4; ++dt)
          oacc[dt][qn] = mfma16(pf, vfg[dt], oacc[dt][qn]);
      }
    }
  }

  // --- epilogue: combine kh2 halves through LDS (l already full per wave)
  __syncthreads();  // all staging reads done; smem reusable
  if (mrow == 0) {
#pragma unroll
    for (int qn = 0; qn < 2; ++qn)
#pragma unroll
      for (int r = 0; r < 4; ++r)
        lbuf[kh2 * 128 + qh * 32 + qn * 16 + quad * 4 + r] = lacc[qn][r];
  }
  if (kh2 == 1) {
#pragma unroll
    for (int dt = 0; dt < 4; ++dt)
#pragma unroll
      for (int qn = 0; qn < 2; ++qn)
#pragma unroll
        for (int r = 0; r < 4; ++r)
          Obuf[(qh * 32 + qn * 16 + quad * 4 + r) * 65 + dt * 16 + mrow] =
              oacc[dt][qn][r];
  }
  __syncthreads();
  if (kh2 == 0) {
#pragma unroll
    for (int qn = 0; qn < 2; ++qn) {
#pragma unroll
      for (int r = 0; r < 4; ++r) {
        int qrow = qh * 32 + qn * 16 + quad * 4 + r;
        float l = lbuf[qrow] + lbuf[128 + qrow];
        int qg = b * 2048 + q0 + qrow;
        float inv = qmask[qg] / l;
#pragma unroll
        for (int dt = 0; dt < 4; ++dt) {
          int idx = qg * 512 + h * 64 + dt * 16 + mrow;
          out[idx] =
              (oacc[dt][qn][r] + Obuf[qrow * 65 + dt * 16 + mrow]) * inv +
              queries[idx];
        }
      }
    }
  }
}

// ---------------------------------------------------------------------------
// Kernel 4: LayerNorm (unbiased std, eps added to std), in-place on d_out.
// ---------------------------------------------------------------------------
__global__ __launch_bounds__(256) void ln_kernel(float* __restrict__ out,
                                                 const float* __restrict__ gamma,
                                                 const float* __restrict__ beta) {
  int row = blockIdx.x * 4 + (threadIdx.x >> 6);
  int lane = threadIdx.x & 63;
  float* p = out + row * 512;
  float4 v1 = ((const float4*)p)[lane];
  float4 v2 = ((const float4*)p)[64 + lane];
  float s = v1.x + v1.y + v1.z + v1.w + v2.x + v2.y + v2.z + v2.w;
  float sq = v1.x * v1.x + v1.y * v1.y + v1.z * v1.z + v1.w * v1.w +
             v2.x * v2.x + v2.y * v2.y + v2.z * v2.z + v2.w * v2.w;
#pragma unroll
  for (int off = 32; off > 0; off >>= 1) {
    s += __shfl_xor(s, off);
    sq += __shfl_xor(sq, off);
  }
  float mean = s * (1.f / 512.f);
  float var = fmaxf((sq - 512.f * mean * mean) * (1.f / 511.f), 0.f);
  float inv = 1.f / (sqrtf(var) + 1e-8f);
  float4 g1 = ((const float4*)gamma)[lane];
  float4 g2 = ((const float4*)gamma)[64 + lane];
  float4 b1 = ((const float4*)beta)[lane];
  float4 b2 = ((const float4*)beta)[64 + lane];
  v1.x = g1.x * (v1.x - mean) * inv + b1.x;
  v1.y = g1.y * (v1.y - mean) * inv + b1.y;
  v1.z = g1.z * (v1.z - mean) * inv + b1.z;
  v1.w = g1.w * (v1.w - mean) * inv + b1.w;
  v2.x = g2.x * (v2.x - mean) * inv + b2.x;
  v2.y = g2.y * (v2.y - mean) * inv + b2.y;
  v2.z = g2.z * (v2.z - mean) * inv + b2.z;
  v2.w = g2.w * (v2.w - mean) * inv + b2.w;
  ((float4*)p)[lane] = v1;
  ((float4*)p)[64 + lane] = v2;
}

// ---------------------------------------------------------------------------
extern "C" void kernel_launch(void* const* d_in, const int* in_sizes, int n_in,
                              void* d_out, int out_size, void* d_ws, size_t ws_size,
                              hipStream_t stream) {
  (void)in_sizes; (void)n_in; (void)out_size; (void)ws_size;
  const float* queries = (const float*)d_in[0];
  const float* keys    = (const float*)d_in[1];
  const float* values  = (const float*)d_in[2];
  const float* Wq = (const float*)d_in[3];
  const float* bq = (const float*)d_in[4];
  const float* Wk = (const float*)d_in[5];
  const float* bk = (const float*)d_in[6];
  const float* Wv = (const float*)d_in[7];
  const float* bv = (const float*)d_in[8];
  const float* gamma = (const float*)d_in[9];
  const float* beta  = (const float*)d_in[10];
  float* out = (float*)d_out;

  char* ws = (char*)d_ws;
  unsigned short* Qb = (unsigned short*)(ws);                    // 8 MB
  unsigned short* Kb = (unsigned short*)(ws + 8 * 1024 * 1024);  // 8 MB
  unsigned short* Vt = (unsigned short*)(ws + 16 * 1024 * 1024); // 8 MB
  unsigned short* Wt = (unsigned short*)(ws + 24 * 1024 * 1024); // 1.5 MB
  float* qmask = (float*)(ws + 24 * 1024 * 1024 + 3 * 512 * 512 * 2);
  float* kbias = qmask + 8192;

  wt_kernel<<<384, 256, 0, stream>>>(Wq, Wk, Wv, Wt);
  proj_kernel<<<dim3(192, 4), 256, 0, stream>>>(queries, keys, values, bq, bk, bv,
                                                Wt, Qb, Kb, Vt, qmask, kbias);
  attn_kernel<<<dim3(32, 16), 512, 0, stream>>>(Qb, Kb, Vt, qmask, kbias, queries, out);
  ln_kernel<<<2048, 256, 0, stream>>>(out, gamma, beta);
}